// Round 1
// 835.201 us; speedup vs baseline: 1.0980x; 1.0980x over previous
//
#include <hip/hip_runtime.h>
#include <hip/hip_fp16.h>

#define T_ 512
#define B_ 512
#define D_ 300
#define H_ 128
#define E_ 64
#define EGO_ 12
#define DH_ 428      // D_+H_
#define BD_ 153600   // B_*D_

typedef __attribute__((ext_vector_type(2))) _Float16 half2_t;
typedef __attribute__((ext_vector_type(8))) _Float16 half8_t;
typedef __attribute__((ext_vector_type(4))) float float4_t;

__device__ __forceinline__ unsigned pack2(float a, float b) {
  __half2 h = __floats2half2_rn(a, b);
  return __builtin_bit_cast(unsigned, h);
}
__device__ __forceinline__ half8_t h8(uint4 u) {
  return __builtin_bit_cast(half8_t, u);
}
__device__ __forceinline__ float sigm(float x) {
  float e = __builtin_amdgcn_exp2f(-1.4426950408889634f * x);
  return __builtin_amdgcn_rcpf(1.0f + e);
}
__device__ __forceinline__ float tanh_(float x) {
  float e = __builtin_amdgcn_exp2f(2.8853900817779268f * x);
  return 1.0f - 2.0f * __builtin_amdgcn_rcpf(1.0f + e);
}

// ---------------- prefix sums of len_sequence -> ws ----------------
__global__ void prefix_k(const int* __restrict__ L, int* __restrict__ pfx) {
  __shared__ int s[T_];
  int t = threadIdx.x;
  s[t] = L[t];
  __syncthreads();
  for (int off = 1; off < T_; off <<= 1) {
    int v = 0;
    if (t >= off) v = s[t - off];
    __syncthreads();
    s[t] += v;
    __syncthreads();
  }
  if (t == 0) pfx[0] = 0;
  pfx[t + 1] = s[t];
}

// ---------------- LSTM scan v4 ----------------------------------------------
// 256 blocks x 256 threads (4 waves), 2 batch rows/block. Batch rows now sit at
// M-rows 0 and 4 of the padded 16-row tile, so their C-fragments land in quad 0
// and quad 1 respectively (C row = quad*4 + reg). The activation chain (the
// dominant VALU cost: exp2/rcp at quarter rate) thus spreads over 32 lanes with
// 2 gate-sets each instead of 16 lanes with 4 -> ~half the per-step VALU issue.
// Biases are folded into the accumulator init (C-in of the first MFMA).
#define WS_ 84   // dword stride per row: 336B (16B-aligned), uniform bank spread
__launch_bounds__(256, 1)
__global__ void scan_k(const float* __restrict__ state,
                       const float* __restrict__ h0,
                       const float* __restrict__ c0,
                       const int* __restrict__ lens,
                       const float* __restrict__ W_ih,
                       const float* __restrict__ W_hh,
                       const float* __restrict__ b_ih,
                       const float* __restrict__ b_hh,
                       const float* __restrict__ W_emb,
                       const float* __restrict__ b_emb,
                       const int* __restrict__ pfx,
                       float* __restrict__ out) {
  __shared__ __align__(16) unsigned hb[2][16][WS_];  // fp16x2; dw<64=h, 64..69=x, rest 0
  __shared__ int pfx_s[T_], len_s[T_];

  const int tid  = threadIdx.x;
  const int lane = tid & 63;
  const int w    = tid >> 6;
  const int n16  = lane & 15;
  const int quad = lane >> 4;
  const int b0   = blockIdx.x * 2;

  // ---- weight-stationary gate B-fragments: tile (c,p), 5 K-slices (K=160)
  uint4 bfr[4][2][5];
  float bias[4][2];
#pragma unroll
  for (int c = 0; c < 4; ++c) {
#pragma unroll
    for (int p = 0; p < 2; ++p) {
      const int g = c * 128 + w * 32 + 2 * n16 + p;
      bias[c][p] = b_ih[g] + b_hh[g];
#pragma unroll
      for (int s = 0; s < 5; ++s) {
        unsigned pk[4];
#pragma unroll
        for (int pp = 0; pp < 4; ++pp) {
          const int k0 = s * 32 + quad * 8 + 2 * pp;   // even
          float f0 = 0.f, f1 = 0.f;
          if (k0 < 128) { f0 = W_hh[g * H_ + k0]; f1 = W_hh[g * H_ + k0 + 1]; }
          else if (k0 < 140) {
            f0 = W_ih[g * EGO_ + (k0 - 128)];
            if (k0 + 1 < 140) f1 = W_ih[g * EGO_ + (k0 - 127)];
          }
          pk[pp] = pack2(f0, f1);
        }
        bfr[c][p][s] = make_uint4(pk[0], pk[1], pk[2], pk[3]);
      }
    }
  }
  // ---- epilogue B-fragments (rnn half of W_emb), e = w*16+n16
  uint4 efr[4];
  const int e_ = w * 16 + n16;
  const float bemb = b_emb[e_];
#pragma unroll
  for (int s = 0; s < 4; ++s) {
    unsigned pk[4];
#pragma unroll
    for (int pp = 0; pp < 4; ++pp) {
      const int k0 = s * 32 + quad * 8 + 2 * pp;
      pk[pp] = pack2(W_emb[e_ * DH_ + D_ + k0], W_emb[e_ * DH_ + D_ + k0 + 1]);
    }
    efr[s] = make_uint4(pk[0], pk[1], pk[2], pk[3]);
  }

  // ---- LDS init: zero both buffers fully, then fill buf0 rows 0,4
  for (int i = tid; i < 2 * 16 * WS_; i += 256) ((unsigned*)hb)[i] = 0u;
  for (int i = tid; i < T_; i += 256) { pfx_s[i] = pfx[i]; len_s[i] = lens[i]; }
  __syncthreads();
  if (tid < 128) {
    const int r = tid >> 6, d = tid & 63;
    float2 v = ((const float2*)(h0 + (b0 + r) * H_))[d];
    hb[0][4 * r][d] = pack2(v.x, v.y);
  }
  float2 xheld = make_float2(0.f, 0.f);
  if (tid >= 16 && tid < 28) {   // wave0/quad1 lanes do x staging
    const int j = tid - 16, row = j / 6, jj = j % 6;
    float2 v = ((const float2*)(state + (b0 + row) * D_))[jj];
    hb[0][4 * row][64 + jj] = pack2(v.x, v.y);
    xheld = ((const float2*)(state + BD_ + (b0 + row) * D_))[jj];
  }
  float cst[2] = {0.f, 0.f};
  if (quad < 2) {
#pragma unroll
    for (int p = 0; p < 2; ++p)
      cst[p] = c0[(b0 + quad) * H_ + w * 32 + 2 * n16 + p];
  }
  __syncthreads();

#pragma unroll 1
  for (int t = 0; t < T_; ++t) {
    const int pb = t & 1;
    // prefetch x(t+2)
    float2 xnew = xheld;
    if (tid >= 16 && tid < 28) {
      const int j = tid - 16, row = j / 6, jj = j % 6;
      const int ttx = (t + 2 < T_) ? t + 2 : T_ - 1;
      xnew = ((const float2*)(state + (size_t)ttx * BD_ + (b0 + row) * D_))[jj];
    }

    // ---- A-fragments from current buffer (h(t-1) | x(t) | 0)
    uint4 a[5];
#pragma unroll
    for (int s = 0; s < 5; ++s)
      a[s] = *(const uint4*)(&hb[pb][n16][s * 16 + quad * 4]);

    // ---- epilogue for t-1 (rnn-part of output row pfx[t-1]+b), uses h(t-1)
    if (t > 0) {
      float4_t ea = (float4_t){bemb, bemb, bemb, bemb};
#pragma unroll
      for (int s = 0; s < 4; ++s)
        ea = __builtin_amdgcn_mfma_f32_16x16x32_f16(h8(a[s]), h8(efr[s]), ea, 0, 0, 0);
      if (quad < 2) {
        const int Lt = len_s[t - 1];
        if (b0 + quad < Lt)
          out[((size_t)pfx_s[t - 1] + b0 + quad) * E_ + e_] = ea[0];
      }
    }

    // ---- gates(t), bias folded into C-in
    float4_t acc[4][2];
#pragma unroll
    for (int c = 0; c < 4; ++c)
#pragma unroll
      for (int p = 0; p < 2; ++p)
        acc[c][p] = (float4_t){bias[c][p], bias[c][p], bias[c][p], bias[c][p]};
#pragma unroll
    for (int s = 0; s < 5; ++s) {
      const half8_t ah = h8(a[s]);
#pragma unroll
      for (int c = 0; c < 4; ++c)
#pragma unroll
        for (int p = 0; p < 2; ++p)
          acc[c][p] = __builtin_amdgcn_mfma_f32_16x16x32_f16(ah, h8(bfr[c][p][s]), acc[c][p], 0, 0, 0);
    }

    // ---- in-lane c/h update: quad q<2 owns batch row b0+q (M-row 4q, reg 0)
    if (quad < 2) {
      float hp[2];
#pragma unroll
      for (int p = 0; p < 2; ++p) {
        const float gi = acc[0][p][0];
        const float gf = acc[1][p][0];
        const float gg = acc[2][p][0];
        const float go = acc[3][p][0];
        const float cc = sigm(gf) * cst[p] + sigm(gi) * tanh_(gg);
        cst[p] = cc;
        hp[p] = sigm(go) * tanh_(cc);
      }
      hb[1 - pb][quad * 4][w * 16 + n16] = pack2(hp[0], hp[1]);
    }
    // stage x(t+1) into next buffer
    if (tid >= 16 && tid < 28) {
      const int j = tid - 16, row = j / 6, jj = j % 6;
      hb[1 - pb][4 * row][64 + jj] = pack2(xheld.x, xheld.y);
      xheld = xnew;
    }
    __syncthreads();   // writes to buf 1-pb visible; all reads of buf pb done
  }

  // ---- final epilogue for t = T-1 (h(511) lives in buffer T_&1 == 0)
  {
    float4_t ea = (float4_t){bemb, bemb, bemb, bemb};
#pragma unroll
    for (int s = 0; s < 4; ++s) {
      uint4 a = *(const uint4*)(&hb[0][n16][s * 16 + quad * 4]);
      ea = __builtin_amdgcn_mfma_f32_16x16x32_f16(h8(a), h8(efr[s]), ea, 0, 0, 0);
    }
    if (quad < 2) {
      const int Lt = len_s[T_ - 1];
      if (b0 + quad < Lt)
        out[((size_t)pfx_s[T_ - 1] + b0 + quad) * E_ + e_] = ea[0];
    }
  }
}

// ---------------- state-part of output (MFMA): out[r,:] += state[j,b,:] @ W_emb[:,:300]^T
// v2: persistent grid-stride (768 blocks = 3/CU). B-fragments + pfx->LDS built
// ONCE per block. Per tile: per-lane 9-step LDS bsearch, A loaded DIRECTLY into
// registers in MFMA fragment layout (lane (n16,quad) reads row n16, floats
// [quad*8+32s, +8) -> 128B-contiguous per row, coalesced), no LDS staging, no
// per-tile barriers. k>=300 tail zeroed in-register (B-frags are zero there too).
#define ER_ 16
__launch_bounds__(256, 3)
__global__ void emb_state_k(const float* __restrict__ state,
                            const float* __restrict__ W_emb,
                            const int* __restrict__ pfx,
                            float* __restrict__ out, int N) {
  __shared__ int pfx_s[T_ + 1];

  const int tid  = threadIdx.x;
  const int lane = tid & 63;
  const int w    = tid >> 6;
  const int n16  = lane & 15;
  const int quad = lane >> 4;

  for (int i = tid; i <= T_; i += 256) pfx_s[i] = pfx[i];

  // ---- B-fragments: 10 K-slices of W_emb state-part, e = w*16+n16 (built once)
  uint4 efr[10];
  const int e_ = w * 16 + n16;
#pragma unroll
  for (int s = 0; s < 10; ++s) {
    unsigned pk[4];
#pragma unroll
    for (int pp = 0; pp < 4; ++pp) {
      const int k0 = s * 32 + quad * 8 + 2 * pp;   // even
      float f0 = 0.f, f1 = 0.f;
      if (k0 < D_) {
        f0 = W_emb[e_ * DH_ + k0];
        if (k0 + 1 < D_) f1 = W_emb[e_ * DH_ + k0 + 1];
      }
      pk[pp] = pack2(f0, f1);
    }
    efr[s] = make_uint4(pk[0], pk[1], pk[2], pk[3]);
  }
  __syncthreads();

  const int ntiles = (N + ER_ - 1) / ER_;
  for (int tile = blockIdx.x; tile < ntiles; tile += gridDim.x) {
    const int r0 = tile * ER_;
    // ---- per-lane decode of the A-row this lane feeds (row n16 of the tile)
    int rA = r0 + n16;
    if (rA > N - 1) rA = N - 1;
    int lo = 0, hi = T_;
#pragma unroll
    for (int it = 0; it < 9; ++it) {   // 2^9 = T_
      const int mid = (lo + hi) >> 1;
      if (pfx_s[mid] <= rA) lo = mid; else hi = mid;
    }
    const float4* sp4 =
        (const float4*)(state + ((size_t)(rA - pfx_s[lo]) * B_ + lo) * D_) + quad * 2;

    // ---- direct-to-register A loads (coalesced: 16 rows x 128B per wave/slice)
    float4 a0[10], a1[10];
#pragma unroll
    for (int s = 0; s < 9; ++s) { a0[s] = sp4[8 * s]; a1[s] = sp4[8 * s + 1]; }
    {
      const float4 z = make_float4(0.f, 0.f, 0.f, 0.f);
      a0[9] = (quad < 2) ? sp4[72] : z;   // floats 288..299 (k<300 only)
      a1[9] = (quad == 0) ? sp4[73] : z;
    }

    // ---- 10 MFMAs, 2 independent chains
    float4_t acc0 = (float4_t){0.f, 0.f, 0.f, 0.f};
    float4_t acc1 = (float4_t){0.f, 0.f, 0.f, 0.f};
#pragma unroll
    for (int s = 0; s < 10; ++s) {
      uint4 ua;
      ua.x = pack2(a0[s].x, a0[s].y);
      ua.y = pack2(a0[s].z, a0[s].w);
      ua.z = pack2(a1[s].x, a1[s].y);
      ua.w = pack2(a1[s].z, a1[s].w);
      if (s & 1) acc1 = __builtin_amdgcn_mfma_f32_16x16x32_f16(h8(ua), h8(efr[s]), acc1, 0, 0, 0);
      else       acc0 = __builtin_amdgcn_mfma_f32_16x16x32_f16(h8(ua), h8(efr[s]), acc0, 0, 0, 0);
    }
#pragma unroll
    for (int r = 0; r < 4; ++r) {
      const int R = r0 + quad * 4 + r;
      if (R < N) out[(size_t)R * E_ + e_] += acc0[r] + acc1[r];
    }
  }
}

extern "C" void kernel_launch(void* const* d_in, const int* in_sizes, int n_in,
                              void* d_out, int out_size, void* d_ws, size_t ws_size,
                              hipStream_t stream) {
  const float* state = (const float*)d_in[0];
  const float* h0    = (const float*)d_in[1];
  const float* c0    = (const float*)d_in[2];
  const int*   lens  = (const int*)d_in[3];
  const float* W_ih  = (const float*)d_in[4];
  const float* W_hh  = (const float*)d_in[5];
  const float* b_ih  = (const float*)d_in[6];
  const float* b_hh  = (const float*)d_in[7];
  const float* W_emb = (const float*)d_in[8];
  const float* b_emb = (const float*)d_in[9];
  float* out = (float*)d_out;
  int* pfx = (int*)d_ws;            // 513 ints
  const int N = out_size / E_;

  prefix_k<<<1, T_, 0, stream>>>(lens, pfx);
  scan_k<<<B_ / 2, 256, 0, stream>>>(state, h0, c0, lens, W_ih, W_hh, b_ih, b_hh,
                                     W_emb, b_emb, pfx, out);
  const int ntiles = (N + ER_ - 1) / ER_;
  const int g = ntiles < 768 ? ntiles : 768;
  emb_state_k<<<g, 256, 0, stream>>>(state, W_emb, pfx, out, N);
}